// Round 3
// baseline (57.895 us; speedup 1.0000x reference)
//
#include <hip/hip_runtime.h>

// B=16, K=4, NQ=10, DIM=1024. U = Rx(w0) ⊗ ... ⊗ Rx(w9) @ real state.
// Gate q acts on bit (NQ-1-q); amp = lane*16 + r (lane 0..63, r 0..15).
//   q=0..5: stride 512..16  -> cross-lane, __shfl_xor mask = 1<<(5-q)
//   q=6..9: stride 8..1     -> in-register pair update on r
// Output layout (verified R2): PLANAR complex64 = [all re (BK*DIM)][all im (BK*DIM)].
constexpr int BK  = 16 * 4;
constexpr int NQ  = 10;
constexpr int DIM = 1 << NQ;  // 1024

__global__ __launch_bounds__(64)
void rx_layer_kernel(const float* __restrict__ weights,  // (BK, NQ)
                     const float* __restrict__ state,    // (BK, DIM) real
                     float* __restrict__ out_re,         // (BK, DIM)
                     float* __restrict__ out_im)         // (BK, DIM)
{
    const int bk   = blockIdx.x;   // one wave per statevector
    const int lane = threadIdx.x;  // 0..63

    float xr[16], xi[16];

    // Load 16 consecutive amps per lane as 4x float4 (contiguous 4 KB per wave).
    const float4* st = reinterpret_cast<const float4*>(state + bk * DIM) + lane * 4;
    #pragma unroll
    for (int j = 0; j < 4; ++j) {
        float4 v = st[j];
        xr[4*j+0] = v.x; xr[4*j+1] = v.y; xr[4*j+2] = v.z; xr[4*j+3] = v.w;
    }

    const float* w = weights + bk * NQ;  // wave-uniform

    // Gate 0 (stride 512, lane xor 32): imag still zero -> half-cost butterfly.
    {
        const float wv = w[0];
        const float a = cosf(0.5f * wv), b = sinf(0.5f * wv);
        #pragma unroll
        for (int r = 0; r < 16; ++r) {
            const float pr = __shfl_xor(xr[r], 32, 64);
            xi[r] = -b * pr;
            xr[r] =  a * xr[r];
        }
    }

    // Gates 1..5: cross-lane xor masks 16,8,4,2,1.
    #pragma unroll
    for (int q = 1; q < 6; ++q) {
        const float wv = w[q];
        const float a = cosf(0.5f * wv), b = sinf(0.5f * wv);
        const int mask = 1 << (5 - q);
        #pragma unroll
        for (int r = 0; r < 16; ++r) {
            const float pr = __shfl_xor(xr[r], mask, 64);
            const float pi = __shfl_xor(xi[r], mask, 64);
            const float nr = fmaf(a, xr[r],  b * pi);
            const float ni = fmaf(a, xi[r], -b * pr);
            xr[r] = nr; xi[r] = ni;
        }
    }

    // Gates 6..9: in-register, r-bit strides 8,4,2,1.
    #pragma unroll
    for (int q = 6; q < 10; ++q) {
        const float wv = w[q];
        const float a = cosf(0.5f * wv), b = sinf(0.5f * wv);
        const int s = 1 << (9 - q);
        #pragma unroll
        for (int r = 0; r < 16; ++r) {
            if (!(r & s)) {
                const int r1 = r | s;
                const float x0r = xr[r],  x0i = xi[r];
                const float x1r = xr[r1], x1i = xi[r1];
                xr[r]  = fmaf(a, x0r,  b * x1i);
                xi[r]  = fmaf(a, x0i, -b * x1r);
                xr[r1] = fmaf(a, x1r,  b * x0i);
                xi[r1] = fmaf(a, x1i, -b * x0r);
            }
        }
    }

    // Planar store, 4x float4 per plane per lane.
    float4* orr = reinterpret_cast<float4*>(out_re + bk * DIM) + lane * 4;
    float4* oi  = reinterpret_cast<float4*>(out_im + bk * DIM) + lane * 4;
    #pragma unroll
    for (int j = 0; j < 4; ++j) {
        orr[j] = make_float4(xr[4*j+0], xr[4*j+1], xr[4*j+2], xr[4*j+3]);
        oi[j]  = make_float4(xi[4*j+0], xi[4*j+1], xi[4*j+2], xi[4*j+3]);
    }
}

extern "C" void kernel_launch(void* const* d_in, const int* in_sizes, int n_in,
                              void* d_out, int out_size, void* d_ws, size_t ws_size,
                              hipStream_t stream) {
    const float* weights = (const float*)d_in[0];  // 640 floats
    const float* state   = (const float*)d_in[1];  // 65536 floats
    float* out = (float*)d_out;                    // planar complex64

    rx_layer_kernel<<<BK, 64, 0, stream>>>(weights, state, out, out + BK * DIM);
}